// Round 1
// baseline (106.816 us; speedup 1.0000x reference)
//
#include <hip/hip_runtime.h>

// Causal depthwise conv1d: B=8, C=1024, T=8192, K=4, DIL=1, PAD=3 (left).
// y[b,c,t] = sum_{k=0..3} w[c,k] * x[b,c,t-3+k] + bias[c]   (zero-pad t<0)
// fp32 in/out. Memory-bound: ~512 MB HBM traffic -> ~81 us roofline @6.3 TB/s.

constexpr int Bc = 8;
constexpr int Cc = 1024;
constexpr int Tc = 8192;

__global__ __launch_bounds__(256) void dwconv1d_kernel(
    const float* __restrict__ x,
    const float* __restrict__ w,     // (C,1,4) contiguous -> one float4 per channel
    const float* __restrict__ bias,  // (C,)
    float* __restrict__ y,
    int n4)                          // total float4 outputs = B*C*T/4
{
    const float4* __restrict__ x4 = reinterpret_cast<const float4*>(x);
    const float4* __restrict__ w4 = reinterpret_cast<const float4*>(w);
    float4* __restrict__ y4 = reinterpret_cast<float4*>(y);

    const int stride = gridDim.x * blockDim.x;
    for (int idx = blockIdx.x * blockDim.x + threadIdx.x; idx < n4; idx += stride) {
        const int p   = idx << 2;          // flat element index of out.x
        const int row = p >> 13;           // p / T   (T = 8192)
        const int t0  = p & (Tc - 1);      // p % T
        const int c   = row & (Cc - 1);    // row % C

        float4 cur = x4[idx];
        float4 prev = make_float4(0.f, 0.f, 0.f, 0.f);
        if (t0 != 0) prev = x4[idx - 1];   // causal zero-pad at row start

        const float4 wc = w4[c];           // w[c,0,0..3]
        const float bc  = bias[c];

        float4 out;
        // y[t] = w0*x[t-3] + w1*x[t-2] + w2*x[t-1] + w3*x[t]
        out.x = fmaf(wc.x, prev.y, fmaf(wc.y, prev.z, fmaf(wc.z, prev.w, fmaf(wc.w, cur.x, bc))));
        out.y = fmaf(wc.x, prev.z, fmaf(wc.y, prev.w, fmaf(wc.z, cur.x,  fmaf(wc.w, cur.y, bc))));
        out.z = fmaf(wc.x, prev.w, fmaf(wc.y, cur.x,  fmaf(wc.z, cur.y,  fmaf(wc.w, cur.z, bc))));
        out.w = fmaf(wc.x, cur.x,  fmaf(wc.y, cur.y,  fmaf(wc.z, cur.z,  fmaf(wc.w, cur.w, bc))));

        y4[idx] = out;
    }
}

extern "C" void kernel_launch(void* const* d_in, const int* in_sizes, int n_in,
                              void* d_out, int out_size, void* d_ws, size_t ws_size,
                              hipStream_t stream) {
    const float* x    = (const float*)d_in[0];
    const float* w    = (const float*)d_in[1];
    const float* bias = (const float*)d_in[2];
    float* y = (float*)d_out;

    const int n4 = (Bc * Cc * Tc) / 4;   // 16,777,216
    const int block = 256;
    const int grid = 2048;               // grid-stride: 8 iters/thread
    dwconv1d_kernel<<<grid, block, 0, stream>>>(x, w, bias, y, n4);
}

// Round 2
// 100.372 us; speedup vs baseline: 1.0642x; 1.0642x over previous
//
#include <hip/hip_runtime.h>

// Causal depthwise conv1d: B=8, C=1024, T=8192, K=4, DIL=1, PAD=3 (left).
// y[b,c,t] = sum_{k=0..3} w[c,k] * x[b,c,t-3+k] + bias[c]   (zero-pad t<0)
// fp32 in/out, ~512 MB HBM traffic -> ~81 us roofline @6.3 TB/s copy ceiling.
//
// Layout: one 256-thread block per (b,c) row. Row = 8192 floats = 2048 float4.
// Each thread handles 8 float4s strided by 256 (coalesced). w/bias are
// block-uniform (one scalar load). prev-window comes from __shfl_up of the
// neighbor lane's cur; lane 0 is patched from a wave-uniform boundary load.

constexpr int Cc = 1024;
constexpr int T4 = 2048;   // T/4 float4s per row

__global__ __launch_bounds__(256) void dwconv1d_kernel(
    const float* __restrict__ x,
    const float* __restrict__ w,     // (C,1,4) -> one float4 per channel
    const float* __restrict__ bias,  // (C,)
    float* __restrict__ y)
{
    const int row = blockIdx.x;                  // 0 .. B*C-1
    const int c   = row & (Cc - 1);

    const float4* __restrict__ xr = reinterpret_cast<const float4*>(x) + (size_t)row * T4;
    float4* __restrict__ yr       = reinterpret_cast<float4*>(y) + (size_t)row * T4;

    const float4 wc = reinterpret_cast<const float4*>(w)[c];   // block-uniform
    const float  bc = bias[c];

    const int tid  = threadIdx.x;
    const int lane = tid & 63;

    // Issue all 8 row-strided loads up front (8 KB/wave in flight).
    float4 cur[8];
#pragma unroll
    for (int j = 0; j < 8; ++j)
        cur[j] = xr[tid + j * 256];

#pragma unroll
    for (int j = 0; j < 8; ++j) {
        const int idx = tid + j * 256;

        // Wave-uniform boundary float4 (the float4 just before this wave's
        // span) to patch lane 0. Broadcast load, L1-hit.
        const int wave_base = (tid & ~63) + j * 256;
        float4 bp = make_float4(0.f, 0.f, 0.f, 0.f);
        if (wave_base != 0) bp = xr[wave_base - 1];   // wave-uniform branch

        // prev elements x[4idx-3 .. 4idx-1] live in lane-1's cur[j].yzw
        float py = __shfl_up(cur[j].y, 1);
        float pz = __shfl_up(cur[j].z, 1);
        float pw = __shfl_up(cur[j].w, 1);
        py = (lane == 0) ? bp.y : py;
        pz = (lane == 0) ? bp.z : pz;
        pw = (lane == 0) ? bp.w : pw;

        float4 out;
        out.x = fmaf(wc.x, py,       fmaf(wc.y, pz,       fmaf(wc.z, pw,       fmaf(wc.w, cur[j].x, bc))));
        out.y = fmaf(wc.x, pz,       fmaf(wc.y, pw,       fmaf(wc.z, cur[j].x, fmaf(wc.w, cur[j].y, bc))));
        out.z = fmaf(wc.x, pw,       fmaf(wc.y, cur[j].x, fmaf(wc.z, cur[j].y, fmaf(wc.w, cur[j].z, bc))));
        out.w = fmaf(wc.x, cur[j].x, fmaf(wc.y, cur[j].y,  fmaf(wc.z, cur[j].z, fmaf(wc.w, cur[j].w, bc))));

        yr[idx] = out;
    }
}

extern "C" void kernel_launch(void* const* d_in, const int* in_sizes, int n_in,
                              void* d_out, int out_size, void* d_ws, size_t ws_size,
                              hipStream_t stream) {
    const float* x    = (const float*)d_in[0];
    const float* w    = (const float*)d_in[1];
    const float* bias = (const float*)d_in[2];
    float* y = (float*)d_out;

    const int rows = 8 * Cc;   // B*C = 8192 blocks, one row each
    dwconv1d_kernel<<<rows, 256, 0, stream>>>(x, w, bias, y);
}

// Round 3
// 95.415 us; speedup vs baseline: 1.1195x; 1.0519x over previous
//
#include <hip/hip_runtime.h>

// Causal depthwise conv1d: B=8, C=1024, T=8192, K=4, DIL=1, PAD=3 (left).
// y[b,c,t] = sum_{k=0..3} w[c,k] * x[b,c,t-3+k] + bias[c]   (zero-pad t<0)
// fp32 in/out, ~512 MB HBM traffic -> ~81 us roofline @6.3 TB/s copy ceiling.
//
// One 256-thread block per (b,c) row (2048 float4s, 8 per thread, coalesced).
// w/bias block-uniform. prev window via __shfl_up; lane 0 patched from a
// wave-uniform boundary load. Streaming: nontemporal loads for x, nontemporal
// stores for y (write-once data must not thrash L2/L3 allocation).

constexpr int Cc = 1024;
constexpr int T4 = 2048;   // T/4 float4s per row

typedef float v4f __attribute__((ext_vector_type(4)));

__global__ __launch_bounds__(256) void dwconv1d_kernel(
    const float* __restrict__ x,
    const float* __restrict__ w,     // (C,1,4) -> one v4f per channel
    const float* __restrict__ bias,  // (C,)
    float* __restrict__ y)
{
    const int row = blockIdx.x;                  // 0 .. B*C-1
    const int c   = row & (Cc - 1);

    const v4f* __restrict__ xr = reinterpret_cast<const v4f*>(x) + (size_t)row * T4;
    v4f* __restrict__ yr       = reinterpret_cast<v4f*>(y) + (size_t)row * T4;

    const v4f  wc = reinterpret_cast<const v4f*>(w)[c];   // block-uniform
    const float bc = bias[c];

    const int tid  = threadIdx.x;
    const int lane = tid & 63;

    // Issue all 8 row-strided nontemporal loads up front (8 KB/wave in flight).
    v4f cur[8];
#pragma unroll
    for (int j = 0; j < 8; ++j)
        cur[j] = __builtin_nontemporal_load(xr + tid + j * 256);

#pragma unroll
    for (int j = 0; j < 8; ++j) {
        const int idx = tid + j * 256;

        // Wave-uniform boundary float4 (just before this wave's span) to patch
        // lane 0. Broadcast load, cached path (neighbor wave loaded the line).
        const int wave_base = (tid & ~63) + j * 256;
        v4f bp = (v4f)(0.f);
        if (wave_base != 0) bp = xr[wave_base - 1];   // wave-uniform branch

        // prev elements x[4idx-3 .. 4idx-1] live in lane-1's cur[j][1..3]
        float py = __shfl_up(cur[j][1], 1);
        float pz = __shfl_up(cur[j][2], 1);
        float pw = __shfl_up(cur[j][3], 1);
        py = (lane == 0) ? bp[1] : py;
        pz = (lane == 0) ? bp[2] : pz;
        pw = (lane == 0) ? bp[3] : pw;

        v4f out;
        out[0] = fmaf(wc[0], py,        fmaf(wc[1], pz,        fmaf(wc[2], pw,        fmaf(wc[3], cur[j][0], bc))));
        out[1] = fmaf(wc[0], pz,        fmaf(wc[1], pw,        fmaf(wc[2], cur[j][0], fmaf(wc[3], cur[j][1], bc))));
        out[2] = fmaf(wc[0], pw,        fmaf(wc[1], cur[j][0], fmaf(wc[2], cur[j][1], fmaf(wc[3], cur[j][2], bc))));
        out[3] = fmaf(wc[0], cur[j][0], fmaf(wc[1], cur[j][1], fmaf(wc[2], cur[j][2], fmaf(wc[3], cur[j][3], bc))));

        __builtin_nontemporal_store(out, yr + idx);
    }
}

extern "C" void kernel_launch(void* const* d_in, const int* in_sizes, int n_in,
                              void* d_out, int out_size, void* d_ws, size_t ws_size,
                              hipStream_t stream) {
    const float* x    = (const float*)d_in[0];
    const float* w    = (const float*)d_in[1];
    const float* bias = (const float*)d_in[2];
    float* y = (float*)d_out;

    const int rows = 8 * Cc;   // B*C = 8192 blocks, one row each
    dwconv1d_kernel<<<rows, 256, 0, stream>>>(x, w, bias, y);
}

// Round 4
// 89.940 us; speedup vs baseline: 1.1876x; 1.0609x over previous
//
#include <hip/hip_runtime.h>

// Causal depthwise conv1d: B=8, C=1024, T=8192, K=4, DIL=1, PAD=3 (left).
// y[b,c,t] = sum_{k=0..3} w[c,k] * x[b,c,t-3+k] + bias[c]   (zero-pad t<0)
// fp32 in/out, ~512 MB HBM traffic -> ~81 us roofline @6.3 TB/s copy ceiling.
//
// One 256-thread block per (b,c) row. Each WAVE owns a contiguous 512-float4
// span (8 groups of 64); per group, prev-window halo comes from __shfl_up
// (lanes 1-63) or lane 63 of the previous group's register (lane 0, j>0).
// Only j==0 needs a real boundary load: ONE wave-uniform float4 per wave.
// nt loads/stores keep the write-once/read-once streams out of L2/L3.

constexpr int Cc = 1024;
constexpr int T4 = 2048;   // T/4 float4s per row

typedef float v4f __attribute__((ext_vector_type(4)));

__global__ __launch_bounds__(256) void dwconv1d_kernel(
    const float* __restrict__ x,
    const float* __restrict__ w,     // (C,1,4) -> one v4f per channel
    const float* __restrict__ bias,  // (C,)
    float* __restrict__ y)
{
    const int row = blockIdx.x;                  // 0 .. B*C-1
    const int c   = row & (Cc - 1);

    const v4f* __restrict__ xr = reinterpret_cast<const v4f*>(x) + (size_t)row * T4;
    v4f* __restrict__ yr       = reinterpret_cast<v4f*>(y) + (size_t)row * T4;

    const v4f   wc = reinterpret_cast<const v4f*>(w)[c];   // block-uniform
    const float bc = bias[c];

    const int tid   = threadIdx.x;
    const int lane  = tid & 63;
    const int wbase = (tid >> 6) * 512;          // wave's contiguous span start

    // Single boundary float4 per wave: element just before the wave's span.
    // Wave 0 = row start -> causal zero pad.
    v4f bnd = (v4f)(0.f);
    if (wbase != 0) bnd = xr[wbase - 1];         // wave-uniform

    // Issue all 8 contiguous-group nt loads (8 KB/wave in flight).
    v4f cur[8];
#pragma unroll
    for (int j = 0; j < 8; ++j)
        cur[j] = __builtin_nontemporal_load(xr + wbase + j * 64 + lane);

#pragma unroll
    for (int j = 0; j < 8; ++j) {
        // prev float4 (elements x[4idx-3..4idx-1]):
        //   lanes 1-63: lane-1's cur[j]
        //   lane 0:     lane 63 of cur[j-1] (j>0) or the wave boundary (j==0)
        float py = __shfl_up(cur[j][1], 1);
        float pz = __shfl_up(cur[j][2], 1);
        float pw = __shfl_up(cur[j][3], 1);
        float qy, qz, qw;
        if (j == 0) { qy = bnd[1]; qz = bnd[2]; qw = bnd[3]; }
        else {
            qy = __shfl(cur[j - 1][1], 63);
            qz = __shfl(cur[j - 1][2], 63);
            qw = __shfl(cur[j - 1][3], 63);
        }
        py = lane ? py : qy;
        pz = lane ? pz : qz;
        pw = lane ? pw : qw;

        v4f out;
        out[0] = fmaf(wc[0], py,        fmaf(wc[1], pz,        fmaf(wc[2], pw,        fmaf(wc[3], cur[j][0], bc))));
        out[1] = fmaf(wc[0], pz,        fmaf(wc[1], pw,        fmaf(wc[2], cur[j][0], fmaf(wc[3], cur[j][1], bc))));
        out[2] = fmaf(wc[0], pw,        fmaf(wc[1], cur[j][0], fmaf(wc[2], cur[j][1], fmaf(wc[3], cur[j][2], bc))));
        out[3] = fmaf(wc[0], cur[j][0], fmaf(wc[1], cur[j][1],  fmaf(wc[2], cur[j][2], fmaf(wc[3], cur[j][3], bc))));

        __builtin_nontemporal_store(out, yr + wbase + j * 64 + lane);
    }
}

extern "C" void kernel_launch(void* const* d_in, const int* in_sizes, int n_in,
                              void* d_out, int out_size, void* d_ws, size_t ws_size,
                              hipStream_t stream) {
    const float* x    = (const float*)d_in[0];
    const float* w    = (const float*)d_in[1];
    const float* bias = (const float*)d_in[2];
    float* y = (float*)d_out;

    const int rows = 8 * Cc;   // B*C = 8192 blocks, one row each
    dwconv1d_kernel<<<rows, 256, 0, stream>>>(x, w, bias, y);
}